// Round 11
// baseline (483.308 us; speedup 1.0000x reference)
//
#include <hip/hip_runtime.h>
#include <stdint.h>

typedef __attribute__((ext_vector_type(4))) float f32x4;
typedef __attribute__((ext_vector_type(16))) float f32x16;
typedef __attribute__((ext_vector_type(8))) short s16x8;
typedef __attribute__((ext_vector_type(4))) unsigned int u32x4;

#define D_ 1024
#define LQ 2048
#define HH_ 8
#define HD_ 128

static __device__ __forceinline__ float bf2f(ushort u){
  union { unsigned int i; float f; } v; v.i = ((unsigned int)u) << 16; return v.f;
}
static __device__ __forceinline__ ushort f2bf(float f){
  union { float f; unsigned int i; } v; v.f = f;
  unsigned int r = v.i + 0x7fffu + ((v.i >> 16) & 1u);
  return (ushort)(r >> 16);
}
static __device__ __forceinline__ unsigned int pkbf(float lo, float hi){
  unsigned int r;
  asm("v_cvt_pk_bf16_f32 %0, %1, %2" : "=v"(r) : "v"(lo), "v"(hi));
  return r;
}

// ---- batched: weight fp32->bf16 conversion (7 matrices) + LN1 (4096 rows) --
// Independent ops at the same stream point merged into ONE dispatch (blocks
// [0,896) convert, [896,4992) layernorm) — cuts launch/gap overhead.
// Wq (w==0) pre-scaled by 1/sqrt(HD) so attn skips the S-scale multiply.
struct WP { const float* s[7]; };
__global__ __launch_bounds__(256) void conv_ln(WP wp, ushort* __restrict__ dst,
    const float* __restrict__ x, const float* __restrict__ g,
    const float* __restrict__ bb, ushort* __restrict__ outb){
  int t = threadIdx.x;
  if (blockIdx.x < 896){
    int w = blockIdx.x >> 7, blk = blockIdx.x & 127;
    const float4* s = (const float4*)wp.s[w];
    ushort4* d = (ushort4*)(dst + (size_t)w * 1048576);
    float sc = (w == 0) ? 0.08838834764831845f : 1.0f;
    int base = blk * 2048 + t;
    #pragma unroll
    for (int r = 0; r < 8; r++){
      float4 v = s[base + r * 256];
      ushort4 o; o.x = f2bf(v.x * sc); o.y = f2bf(v.y * sc);
      o.z = f2bf(v.z * sc); o.w = f2bf(v.w * sc);
      d[base + r * 256] = o;
    }
    return;
  }
  int row = blockIdx.x - 896;
  const float4* xr = (const float4*)(x + (size_t)row * D_);
  float4 v = xr[t];
  float s = v.x + v.y + v.z + v.w;
  float sq = v.x*v.x + v.y*v.y + v.z*v.z + v.w*v.w;
  #pragma unroll
  for (int o = 32; o; o >>= 1){ s += __shfl_down(s, o, 64); sq += __shfl_down(sq, o, 64); }
  __shared__ float red[8];
  int lane = t & 63, wv = t >> 6;
  if (!lane){ red[wv] = s; red[wv + 4] = sq; }
  __syncthreads();
  float S = red[0] + red[1] + red[2] + red[3];
  float SQ = red[4] + red[5] + red[6] + red[7];
  float m = S * (1.f / 1024.f);
  float var = SQ * (1.f / 1024.f) - m * m;
  float inv = rsqrtf(var + 1e-8f);
  float4 gv = ((const float4*)g)[t], bv = ((const float4*)bb)[t];
  ushort4 o4;
  o4.x = f2bf((v.x - m) * inv * gv.x + bv.x);
  o4.y = f2bf((v.y - m) * inv * gv.y + bv.y);
  o4.z = f2bf((v.z - m) * inv * gv.z + bv.z);
  o4.w = f2bf((v.w - m) * inv * gv.w + bv.w);
  ((ushort4*)outb)[(size_t)row * 256 + t] = o4;
}

// ---------------- layernorm: fp32 in -> bf16 (or fp32) out ------------------
template<int OUTF>
__global__ __launch_bounds__(256) void ln_kernel(const float* __restrict__ x,
    const float* __restrict__ g, const float* __restrict__ bb,
    float* __restrict__ outf, ushort* __restrict__ outb){
  int row = blockIdx.x, t = threadIdx.x;
  const float4* xr = (const float4*)(x + (size_t)row * D_);
  float4 v = xr[t];
  float s = v.x + v.y + v.z + v.w;
  float sq = v.x*v.x + v.y*v.y + v.z*v.z + v.w*v.w;
  #pragma unroll
  for (int o = 32; o; o >>= 1){ s += __shfl_down(s, o, 64); sq += __shfl_down(sq, o, 64); }
  __shared__ float red[8];
  int lane = t & 63, wv = t >> 6;
  if (!lane){ red[wv] = s; red[wv + 4] = sq; }
  __syncthreads();
  float S = red[0] + red[1] + red[2] + red[3];
  float SQ = red[4] + red[5] + red[6] + red[7];
  float m = S * (1.f / 1024.f);
  float var = SQ * (1.f / 1024.f) - m * m;
  float inv = rsqrtf(var + 1e-8f);
  float4 gv = ((const float4*)g)[t], bv = ((const float4*)bb)[t];
  float4 y;
  y.x = (v.x - m) * inv * gv.x + bv.x;
  y.y = (v.y - m) * inv * gv.y + bv.y;
  y.z = (v.z - m) * inv * gv.z + bv.z;
  y.w = (v.w - m) * inv * gv.w + bv.w;
  if (OUTF){
    ((float4*)outf)[(size_t)row * 256 + t] = y;
  } else {
    ushort4 o4; o4.x = f2bf(y.x); o4.y = f2bf(y.y); o4.z = f2bf(y.z); o4.w = f2bf(y.w);
    ((ushort4*)outb)[(size_t)row * 256 + t] = o4;
  }
}

// ---------------- GEMM 128x128, BK=64, swizzled LDS -------------------------
// EPI 3 = QKUV fused (N=4096, dst/bias by n0>>10; RoPE on Q,K) -> bf16.
// sel==3 (V) blocks: C-tile staged in LDS (stride 129), written TRANSPOSED +
// sigma-permuted straight to Vt.
struct P4 { ushort* d[4]; const float* b[4]; };

template<int EPI, int NB>
__global__ __launch_bounds__(256, 3) void gemm_k(
    const ushort* __restrict__ A, const ushort* __restrict__ W,
    P4 io, const float* __restrict__ resid, float* __restrict__ outf){
  __shared__ ushort smem[16512];         // As[0..8192) | Bs[8192..16384); epi T 128x129
  ushort* As = smem;
  ushort* Bs = smem + 8192;
  int m0 = (blockIdx.x / NB) << 7;
  int n0 = (blockIdx.x % NB) << 7;
  int t = threadIdx.x, lane = t & 63, wv = t >> 6;
  int l15 = lane & 15, quad = lane >> 4;
  int wm = (wv & 1) << 6, wn = (wv >> 1) << 6;
  f32x4 acc[4][4] = {};
  for (int k0 = 0; k0 < 1024; k0 += 64){
    #pragma unroll
    for (int r = 0; r < 4; r++){
      int cb = r * 256 + wv * 64;      // wave-uniform chunk base
      int c = cb + lane;               // chunk id 0..1023
      int row = c >> 3, j = c & 7;
      int kk = ((j ^ (row & 7)) << 3); // swizzled global k-chunk
      __builtin_amdgcn_global_load_lds(
          (const __attribute__((address_space(1))) unsigned int*)(A + (size_t)(m0 + row) * 1024 + k0 + kk),
          (__attribute__((address_space(3))) unsigned int*)&As[cb * 8], 16, 0, 0);
      __builtin_amdgcn_global_load_lds(
          (const __attribute__((address_space(1))) unsigned int*)(W + (size_t)(n0 + row) * 1024 + k0 + kk),
          (__attribute__((address_space(3))) unsigned int*)&Bs[cb * 8], 16, 0, 0);
    }
    __syncthreads();
    #pragma unroll
    for (int kd = 0; kd < 2; kd++){
      s16x8 afr[4], bfr[4];
      #pragma unroll
      for (int mi = 0; mi < 4; mi++){
        int R = wm + mi * 16 + l15;
        afr[mi] = *(const s16x8*)&As[R * 64 + (((kd << 2) | quad) ^ (R & 7)) * 8];
      }
      #pragma unroll
      for (int ni = 0; ni < 4; ni++){
        int R = wn + ni * 16 + l15;
        bfr[ni] = *(const s16x8*)&Bs[R * 64 + (((kd << 2) | quad) ^ (R & 7)) * 8];
      }
      #pragma unroll
      for (int mi = 0; mi < 4; mi++)
        #pragma unroll
        for (int ni = 0; ni < 4; ni++)
          acc[mi][ni] = __builtin_amdgcn_mfma_f32_16x16x32_bf16(afr[mi], bfr[ni], acc[mi][ni], 0, 0, 0);
    }
    __syncthreads();
  }
  int sel = (EPI == 3) ? (n0 >> 10) : 0;
  ushort* dst = io.d[sel];
  const float* bias = io.b[sel];
  int ncol = (EPI == 3) ? (n0 & 1023) : n0;

  if (EPI == 3 && sel == 3){
    // ---- V path: bias-add into LDS tile T[l][d] (stride 129), then write
    // Vt[(b*8+hh)*128 + d][l0 + c] = T[sigma(c)][d]  (sigma swaps key bits 2<->3)
    #pragma unroll
    for (int mi = 0; mi < 4; mi++){
      int lr = wm + mi * 16 + quad * 4;
      #pragma unroll
      for (int ni = 0; ni < 4; ni++){
        int d = wn + ni * 16 + l15;
        float bv = bias[ncol + d];
        #pragma unroll
        for (int r = 0; r < 4; r++)
          smem[(lr + r) * 129 + d] = f2bf(acc[mi][ni][r] + bv);
      }
    }
    __syncthreads();
    int b_ = m0 >> 11, l0 = m0 & 2047;
    int hh = ncol >> 7;
    int d = t >> 1, lh = t & 1;
    ushort* vrow = io.d[3] + ((size_t)((b_ * 8 + hh) * 128 + d)) * 2048 + l0 + lh * 64;
    #pragma unroll
    for (int j = 0; j < 64; j += 2){
      int c = lh * 64 + j;
      int x = c & 15;
      int ls = (c & 112) | ((x & 4) << 1) | ((x & 8) >> 1) | (x & 3);
      unsigned int val = (unsigned int)smem[ls * 129 + d] |
                         ((unsigned int)smem[(ls + 1) * 129 + d] << 16);
      *(unsigned int*)(vrow + j) = val;
    }
    return;
  }

  #pragma unroll
  for (int mi = 0; mi < 4; mi++){
    int gm = m0 + wm + mi * 16 + quad * 4;
    #pragma unroll
    for (int ni = 0; ni < 4; ni++){
      int cn = ncol + wn + ni * 16 + l15;
      float bv = bias[cn];
      if (EPI == 3 && sel == 0) bv *= 0.08838834764831845f;  // Wq pre-scaled
      if (EPI == 3 && sel < 2){
        // fused RoPE: pair (even,odd) cols live in lanes lane^1
        int i2 = (cn & 127) >> 1;
        float freq = __builtin_amdgcn_exp2f(-0.20762050f * (float)i2);  // 10000^(-2i/128)
        int odd = cn & 1;
        #pragma unroll
        for (int r = 0; r < 4; r++){
          float val = acc[mi][ni][r] + bv;
          float pv = __shfl_xor(val, 1, 64);
          int pos = (gm + r) & 2047;
          float ang = (float)pos * freq;
          float sv, cv; __sincosf(ang, &sv, &cv);
          float res = odd ? (pv * sv + val * cv) : (val * cv - pv * sv);
          dst[(size_t)(gm + r) * 1024 + cn] = f2bf(res);
        }
      } else {
        #pragma unroll
        for (int r = 0; r < 4; r++){
          float val = acc[mi][ni][r] + bv;
          size_t o = (size_t)(gm + r) * 1024 + cn;
          if (EPI == 1){ outf[o] = resid[o] + val; }
          else if (EPI == 2){
            float sg = __builtin_amdgcn_rcpf(1.f + __expf(-val));
            dst[o] = f2bf(val * val * sg);
          }
          else { dst[o] = f2bf(val); }
        }
      }
    }
  }
}

// ---------------- GEMM 64x128 tile, BK=64, swizzled (512 blocks) ------------
// EPI: 1 = bias + residual -> fp32 ; 2 = bias + p*silu(p) -> bf16
template<int EPI>
__global__ __launch_bounds__(256, 2) void gemm_k2(
    const ushort* __restrict__ A, const ushort* __restrict__ W,
    const float* __restrict__ bias, ushort* __restrict__ dst,
    const float* __restrict__ resid, float* __restrict__ outf){
  __shared__ ushort As[64 * 64];
  __shared__ ushort Bs[128 * 64];
  int m0 = (blockIdx.x >> 3) << 6;
  int n0 = (blockIdx.x & 7) << 7;
  int t = threadIdx.x, lane = t & 63, wv = t >> 6;
  int l15 = lane & 15, quad = lane >> 4;
  int wm = (wv & 1) << 5, wn = (wv >> 1) << 6;
  f32x4 acc[2][4] = {};
  for (int k0 = 0; k0 < 1024; k0 += 64){
    #pragma unroll
    for (int r = 0; r < 6; r++){
      int cb = (r < 2 ? r * 256 : (r - 2) * 256) + wv * 64;
      int c = cb + lane;
      int row = c >> 3, j = c & 7;
      int kk = ((j ^ (row & 7)) << 3);
      if (r < 2){
        __builtin_amdgcn_global_load_lds(
            (const __attribute__((address_space(1))) unsigned int*)(A + (size_t)(m0 + row) * 1024 + k0 + kk),
            (__attribute__((address_space(3))) unsigned int*)&As[cb * 8], 16, 0, 0);
      } else {
        __builtin_amdgcn_global_load_lds(
            (const __attribute__((address_space(1))) unsigned int*)(W + (size_t)(n0 + row) * 1024 + k0 + kk),
            (__attribute__((address_space(3))) unsigned int*)&Bs[cb * 8], 16, 0, 0);
      }
    }
    __syncthreads();
    #pragma unroll
    for (int kd = 0; kd < 2; kd++){
      s16x8 afr[2], bfr[4];
      #pragma unroll
      for (int mi = 0; mi < 2; mi++){
        int R = wm + mi * 16 + l15;
        afr[mi] = *(const s16x8*)&As[R * 64 + (((kd << 2) | quad) ^ (R & 7)) * 8];
      }
      #pragma unroll
      for (int ni = 0; ni < 4; ni++){
        int R = wn + ni * 16 + l15;
        bfr[ni] = *(const s16x8*)&Bs[R * 64 + (((kd << 2) | quad) ^ (R & 7)) * 8];
      }
      #pragma unroll
      for (int mi = 0; mi < 2; mi++)
        #pragma unroll
        for (int ni = 0; ni < 4; ni++)
          acc[mi][ni] = __builtin_amdgcn_mfma_f32_16x16x32_bf16(afr[mi], bfr[ni], acc[mi][ni], 0, 0, 0);
    }
    __syncthreads();
  }
  #pragma unroll
  for (int mi = 0; mi < 2; mi++){
    int gm = m0 + wm + mi * 16 + quad * 4;
    #pragma unroll
    for (int ni = 0; ni < 4; ni++){
      int cn = n0 + wn + ni * 16 + l15;
      float bv = bias[cn];
      #pragma unroll
      for (int r = 0; r < 4; r++){
        float val = acc[mi][ni][r] + bv;
        size_t o = (size_t)(gm + r) * 1024 + cn;
        if (EPI == 1){ outf[o] = resid[o] + val; }
        else {
          float sg = __builtin_amdgcn_rcpf(1.f + __expf(-val));
          dst[o] = f2bf(val * val * sg);
        }
      }
    }
  }
}

// ---------------- causal silu-attention, split-K, 32x32 MFMA ----------------
// 128-q blocks, 64-key tiles, 4 waves x 32 q-rows (proven load-balanced
// 512-block paired grid; blocks i and i+256 sum to 17 iters at 2 blocks/CU).
// Swapped QK^T (mfma(K,Q) -> S^T, col=q=lane&31) keeps P lane-local;
// in-register cvt_pk pack feeds PV directly (sigma absorbed into Vt).
// S pre-scaled via Wq fold. No setprio: intra-block waves are barrier-
// synced every iter, so priority boosts delay staging (R9 lesson).
__global__ __launch_bounds__(256, 2) void attn_kernel(
    const ushort* __restrict__ Q, const ushort* __restrict__ K,
    const ushort* __restrict__ Vt,
    ushort* __restrict__ Po0, ushort* __restrict__ Po1){
  __shared__ ushort Ks[2][64 * 128];
  __shared__ ushort Vs[2][128 * 64];
  int t = threadIdx.x, lane = t & 63, wv = t >> 6;
  int l31 = lane & 31, h = lane >> 5;
  int idx = blockIdx.x;
  int bh = idx & 15;
  int s = idx >> 4;
  int qt = (s < 16) ? (15 - (s >> 1)) : ((s - 16) >> 1);
  int half = s & 1;
  int ntiles = 2 * qt + 2;
  int c0 = qt + 1;
  int klo = half ? c0 : 0;
  int khi = half ? ntiles : c0;
  if (klo >= khi) return;
  int b = bh >> 3, hh = bh & 7;
  int q0 = qt << 7;

  // Q fragments (B-operand): col = q = lane&31, k(hd) = 16*kd + 8*h + j
  s16x8 qf[8];
  const ushort* qbase = Q + (size_t)(b * LQ + q0 + (wv << 5) + l31) * D_ + hh * HD_;
  #pragma unroll
  for (int kd = 0; kd < 8; kd++) qf[kd] = *(const s16x8*)(qbase + kd * 16 + h * 8);

  auto STAGE = [&](int p, int kt){
    int k0 = kt << 6;
    #pragma unroll
    for (int r = 0; r < 4; r++){
      int cb = r * 256 + (wv << 6);    // wave-uniform slot base
      int c = cb + lane;               // 16B slot id 0..1023
      int R = c >> 4, sl = c & 15;
      int gg = sl ^ (R & 7);           // swizzled source granule
      __builtin_amdgcn_global_load_lds(
          (const __attribute__((address_space(1))) unsigned int*)(K + (size_t)(b * LQ + k0 + R) * D_ + hh * HD_ + gg * 8),
          (__attribute__((address_space(3))) unsigned int*)&Ks[p][cb * 8], 16, 0, 0);
    }
    #pragma unroll
    for (int r = 0; r < 4; r++){
      int cb = r * 256 + (wv << 6);
      int c = cb + lane;
      int R = c >> 3, sl = c & 7;
      int gg = sl ^ (R & 7);
      __builtin_amdgcn_global_load_lds(
          (const __attribute__((address_space(1))) unsigned int*)(Vt + (size_t)(bh * HD_ + R) * LQ + k0 + gg * 8),
          (__attribute__((address_space(3))) unsigned int*)&Vs[p][cb * 8], 16, 0, 0);
    }
  };

  f32x16 acc_o[4] = {};
  int qg = q0 + (wv << 5) + l31;

  STAGE(0, klo);
  __syncthreads();
  for (int kt = klo; kt < khi; kt++){
    int p = (kt - klo) & 1;
    if (kt + 1 < khi) STAGE(p ^ 1, kt + 1);
    // swapped QK^T: S^T[key][q], col = q = lane&31
    f32x16 sacc[2] = {};
    #pragma unroll
    for (int kd = 0; kd < 8; kd++){
      #pragma unroll
      for (int kb = 0; kb < 2; kb++){
        int R = (kb << 5) + l31;
        s16x8 af = *(const s16x8*)&Ks[p][(R * 16 + (((kd << 1) | h) ^ (R & 7))) * 8];
        sacc[kb] = __builtin_amdgcn_mfma_f32_32x32x16_bf16(af, qf[kd], sacc[kb], 0, 0, 0);
      }
    }
    // silu + causal mask + in-register pack to PV A-fragments (S pre-scaled)
    int k0 = kt << 6;
    s16x8 pf[4];
    #pragma unroll
    for (int kb = 0; kb < 2; kb++){
      float pvv[16];
      #pragma unroll
      for (int r = 0; r < 16; r++){
        int kg = k0 + (kb << 5) + (r & 3) + ((r >> 2) << 3) + (h << 2);
        float sv = sacc[kb][r];
        float pp = sv * __builtin_amdgcn_rcpf(1.f + __expf(-sv));
        pvv[r] = (kg <= qg) ? pp : 0.f;
      }
      #pragma unroll
      for (int cc = 0; cc < 2; cc++){
        union { u32x4 u; s16x8 v; } w;
        w.u[0] = pkbf(pvv[cc*8+0], pvv[cc*8+1]);
        w.u[1] = pkbf(pvv[cc*8+2], pvv[cc*8+3]);
        w.u[2] = pkbf(pvv[cc*8+4], pvv[cc*8+5]);
        w.u[3] = pkbf(pvv[cc*8+6], pvv[cc*8+7]);
        pf[(kb << 1) | cc] = w.v;
      }
    }
    // PV: O[q][d] += P * V  (V columns sigma-permuted to match pf key order)
    #pragma unroll
    for (int kv = 0; kv < 4; kv++){
      #pragma unroll
      for (int nt = 0; nt < 4; nt++){
        int R = (nt << 5) + l31;
        s16x8 vf = *(const s16x8*)&Vs[p][(R * 8 + (((kv << 1) | h) ^ (R & 7))) * 8];
        acc_o[nt] = __builtin_amdgcn_mfma_f32_32x32x16_bf16(pf[kv], vf, acc_o[nt], 0, 0, 0);
      }
    }
    __syncthreads();
  }
  ushort* Po = half ? Po1 : Po0;
  #pragma unroll
  for (int nt = 0; nt < 4; nt++){
    #pragma unroll
    for (int r = 0; r < 16; r++){
      int qq = q0 + (wv << 5) + (r & 3) + ((r >> 2) << 3) + (h << 2);
      int dd = (nt << 5) + l31;
      Po[(size_t)(b * LQ + qq) * D_ + hh * HD_ + dd] = f2bf(acc_o[nt][r]);
    }
  }
}

// ---------------- attn partial reduce: (P0 + P1) * U -> bf16 ----------------
__global__ __launch_bounds__(256) void attn_reduce(
    const ushort* __restrict__ Po0, const ushort* __restrict__ Po1,
    const ushort* __restrict__ U, ushort* __restrict__ Aout){
  int i = (blockIdx.x * 256 + threadIdx.x) * 4;   // 4M elems total
  ushort4 p0 = *(const ushort4*)(Po0 + i);
  ushort4 p1 = *(const ushort4*)(Po1 + i);
  float v0 = bf2f(p0.x) + bf2f(p1.x);
  float v1 = bf2f(p0.y) + bf2f(p1.y);
  float v2 = bf2f(p0.z) + bf2f(p1.z);
  float v3 = bf2f(p0.w) + bf2f(p1.w);
  ushort4 u = *(const ushort4*)(U + i);
  ushort4 o;
  o.x = f2bf(v0 * bf2f(u.x)); o.y = f2bf(v1 * bf2f(u.y));
  o.z = f2bf(v2 * bf2f(u.z)); o.w = f2bf(v3 * bf2f(u.w));
  *(ushort4*)(Aout + i) = o;
}

// ---------------- launcher --------------------------------------------------
extern "C" void kernel_launch(void* const* d_in, const int* in_sizes, int n_in,
                              void* d_out, int out_size, void* d_ws, size_t ws_size,
                              hipStream_t stream){
  const float* seqs = (const float*)d_in[0];
  const float* bq = (const float*)d_in[3];
  const float* bk = (const float*)d_in[5];
  const float* bu = (const float*)d_in[7];
  const float* bv = (const float*)d_in[9];
  const float* bo = (const float*)d_in[11];
  const float* b1 = (const float*)d_in[13];
  const float* b2 = (const float*)d_in[15];
  const float* ln1g = (const float*)d_in[16];
  const float* ln1b = (const float*)d_in[17];
  const float* ln2g = (const float*)d_in[18];
  const float* ln2b = (const float*)d_in[19];
  const float* lnfg = (const float*)d_in[20];
  const float* lnfb = (const float*)d_in[21];

  char* base = (char*)d_ws;
  const size_t MB = 1u << 20;
  if (ws_size < 78 * MB) return;  // defensive
  ushort* wbf = (ushort*)base;                   // 14 MB
  ushort* h   = (ushort*)(base + 14 * MB);       // 8 MB (ln out; attn Po0; attn out)
  ushort* Qb  = (ushort*)(base + 22 * MB);       // 8 MB (also MLP hidden)
  ushort* Kb  = (ushort*)(base + 30 * MB);       // 8 MB
  ushort* Ub  = (ushort*)(base + 38 * MB);       // 8 MB
  ushort* Vb  = (ushort*)(base + 46 * MB);       // 8 MB (attn Po1)
  ushort* Vt  = (ushort*)(base + 54 * MB);       // 8 MB (written by gemm_k sel==3)
  float*  xb  = (float*)(base + 62 * MB);        // 16 MB
  ushort* ab  = h;

  const size_t DD = 1048576;
  for (int i = 0; i < 2; i++){
    WP wp;
    for (int j = 0; j < 7; j++)
      wp.s[j] = (const float*)d_in[2 + 2 * j] + (size_t)i * DD;
    const ushort* Wl = wbf;
    const float* xin = (i == 0) ? seqs : xb;
    // batched: convert this layer's 7 weight matrices + LN1 (one dispatch)
    conv_ln<<<4992, 256, 0, stream>>>(wp, wbf, xin, ln1g + i * D_, ln1b + i * D_, h);
    // fused QKUV projection (N=4096): RoPE on Q,K; V written transposed to Vt
    P4 io_qkuv = {{Qb, Kb, Ub, Vt}, {bq + i * D_, bk + i * D_, bu + i * D_, bv + i * D_}};
    gemm_k<3, 32><<<1024, 256, 0, stream>>>(h, Wl, io_qkuv, nullptr, nullptr);
    attn_kernel<<<512, 256, 0, stream>>>(Qb, Kb, Vt, ab, Vb);
    attn_reduce<<<4096, 256, 0, stream>>>(ab, Vb, Ub, ab);
    gemm_k2<1><<<512, 256, 0, stream>>>(ab, Wl + 4 * DD, bo + i * D_, nullptr, xin, xb);
    ln_kernel<0><<<4096, 256, 0, stream>>>(xb, ln2g + i * D_, ln2b + i * D_, nullptr, h);
    gemm_k2<2><<<512, 256, 0, stream>>>(h, Wl + 5 * DD, b1 + i * D_, Qb, nullptr, nullptr);
    gemm_k2<1><<<512, 256, 0, stream>>>(Qb, Wl + 6 * DD, b2 + i * D_, nullptr, xb, xb);
  }
  ln_kernel<1><<<4096, 256, 0, stream>>>(xb, lnfg, lnfb, (float*)d_out, nullptr);
}

// Round 12
// 464.442 us; speedup vs baseline: 1.0406x; 1.0406x over previous
//
#include <hip/hip_runtime.h>
#include <stdint.h>

typedef __attribute__((ext_vector_type(4))) float f32x4;
typedef __attribute__((ext_vector_type(16))) float f32x16;
typedef __attribute__((ext_vector_type(8))) short s16x8;
typedef __attribute__((ext_vector_type(4))) unsigned int u32x4;

#define D_ 1024
#define LQ 2048
#define HH_ 8
#define HD_ 128

static __device__ __forceinline__ float bf2f(ushort u){
  union { unsigned int i; float f; } v; v.i = ((unsigned int)u) << 16; return v.f;
}
static __device__ __forceinline__ ushort f2bf(float f){
  union { float f; unsigned int i; } v; v.f = f;
  unsigned int r = v.i + 0x7fffu + ((v.i >> 16) & 1u);
  return (ushort)(r >> 16);
}
static __device__ __forceinline__ unsigned int pkbf(float lo, float hi){
  unsigned int r;
  asm("v_cvt_pk_bf16_f32 %0, %1, %2" : "=v"(r) : "v"(lo), "v"(hi));
  return r;
}

// ---------------- weight fp32 -> bf16 conversion (7 matrices of 1M) --------
// Wq (w==0) is pre-scaled by 1/sqrt(HD) so attn skips the S-scale multiply.
struct WP { const float* s[7]; };
__global__ __launch_bounds__(256) void convert_weights(WP wp, ushort* __restrict__ dst){
  int w = blockIdx.x >> 7, blk = blockIdx.x & 127, t = threadIdx.x;
  const float4* s = (const float4*)wp.s[w];
  ushort4* d = (ushort4*)(dst + (size_t)w * 1048576);
  float sc = (w == 0) ? 0.08838834764831845f : 1.0f;
  int base = blk * 2048 + t;
  #pragma unroll
  for (int r = 0; r < 8; r++){
    float4 v = s[base + r * 256];
    ushort4 o; o.x = f2bf(v.x * sc); o.y = f2bf(v.y * sc);
    o.z = f2bf(v.z * sc); o.w = f2bf(v.w * sc);
    d[base + r * 256] = o;
  }
}

// ---------------- layernorm: fp32 in -> bf16 (or fp32) out ------------------
template<int OUTF>
__global__ __launch_bounds__(256) void ln_kernel(const float* __restrict__ x,
    const float* __restrict__ g, const float* __restrict__ bb,
    float* __restrict__ outf, ushort* __restrict__ outb){
  int row = blockIdx.x, t = threadIdx.x;
  const float4* xr = (const float4*)(x + (size_t)row * D_);
  float4 v = xr[t];
  float s = v.x + v.y + v.z + v.w;
  float sq = v.x*v.x + v.y*v.y + v.z*v.z + v.w*v.w;
  #pragma unroll
  for (int o = 32; o; o >>= 1){ s += __shfl_down(s, o, 64); sq += __shfl_down(sq, o, 64); }
  __shared__ float red[8];
  int lane = t & 63, wv = t >> 6;
  if (!lane){ red[wv] = s; red[wv + 4] = sq; }
  __syncthreads();
  float S = red[0] + red[1] + red[2] + red[3];
  float SQ = red[4] + red[5] + red[6] + red[7];
  float m = S * (1.f / 1024.f);
  float var = SQ * (1.f / 1024.f) - m * m;
  float inv = rsqrtf(var + 1e-8f);
  float4 gv = ((const float4*)g)[t], bv = ((const float4*)bb)[t];
  float4 y;
  y.x = (v.x - m) * inv * gv.x + bv.x;
  y.y = (v.y - m) * inv * gv.y + bv.y;
  y.z = (v.z - m) * inv * gv.z + bv.z;
  y.w = (v.w - m) * inv * gv.w + bv.w;
  if (OUTF){
    ((float4*)outf)[(size_t)row * 256 + t] = y;
  } else {
    ushort4 o4; o4.x = f2bf(y.x); o4.y = f2bf(y.y); o4.z = f2bf(y.z); o4.w = f2bf(y.w);
    ((ushort4*)outb)[(size_t)row * 256 + t] = o4;
  }
}

// ---------------- GEMM 128x128, BK=64, swizzled LDS -------------------------
// EPI 3 = QKUV fused (N=4096, dst/bias by n0>>10; RoPE on Q,K) -> bf16.
// sel==3 (V) blocks: C-tile staged in LDS (stride 129), written TRANSPOSED +
// sigma-permuted straight to Vt.
// __launch_bounds__(256,2): measured best (R1: 43.0-43.1 µs vs 44.3-45.6 at
// (256,3) — the 3/CU variant leaves a ragged 256-block tail; 1024 = 2 full
// passes at 2/CU).
struct P4 { ushort* d[4]; const float* b[4]; };

template<int EPI, int NB>
__global__ __launch_bounds__(256, 2) void gemm_k(
    const ushort* __restrict__ A, const ushort* __restrict__ W,
    P4 io, const float* __restrict__ resid, float* __restrict__ outf){
  __shared__ ushort smem[16512];         // As[0..8192) | Bs[8192..16384); epi T 128x129
  ushort* As = smem;
  ushort* Bs = smem + 8192;
  int m0 = (blockIdx.x / NB) << 7;
  int n0 = (blockIdx.x % NB) << 7;
  int t = threadIdx.x, lane = t & 63, wv = t >> 6;
  int l15 = lane & 15, quad = lane >> 4;
  int wm = (wv & 1) << 6, wn = (wv >> 1) << 6;
  f32x4 acc[4][4] = {};
  for (int k0 = 0; k0 < 1024; k0 += 64){
    #pragma unroll
    for (int r = 0; r < 4; r++){
      int cb = r * 256 + wv * 64;      // wave-uniform chunk base
      int c = cb + lane;               // chunk id 0..1023
      int row = c >> 3, j = c & 7;
      int kk = ((j ^ (row & 7)) << 3); // swizzled global k-chunk
      __builtin_amdgcn_global_load_lds(
          (const __attribute__((address_space(1))) unsigned int*)(A + (size_t)(m0 + row) * 1024 + k0 + kk),
          (__attribute__((address_space(3))) unsigned int*)&As[cb * 8], 16, 0, 0);
      __builtin_amdgcn_global_load_lds(
          (const __attribute__((address_space(1))) unsigned int*)(W + (size_t)(n0 + row) * 1024 + k0 + kk),
          (__attribute__((address_space(3))) unsigned int*)&Bs[cb * 8], 16, 0, 0);
    }
    __syncthreads();
    #pragma unroll
    for (int kd = 0; kd < 2; kd++){
      s16x8 afr[4], bfr[4];
      #pragma unroll
      for (int mi = 0; mi < 4; mi++){
        int R = wm + mi * 16 + l15;
        afr[mi] = *(const s16x8*)&As[R * 64 + (((kd << 2) | quad) ^ (R & 7)) * 8];
      }
      #pragma unroll
      for (int ni = 0; ni < 4; ni++){
        int R = wn + ni * 16 + l15;
        bfr[ni] = *(const s16x8*)&Bs[R * 64 + (((kd << 2) | quad) ^ (R & 7)) * 8];
      }
      #pragma unroll
      for (int mi = 0; mi < 4; mi++)
        #pragma unroll
        for (int ni = 0; ni < 4; ni++)
          acc[mi][ni] = __builtin_amdgcn_mfma_f32_16x16x32_bf16(afr[mi], bfr[ni], acc[mi][ni], 0, 0, 0);
    }
    __syncthreads();
  }
  int sel = (EPI == 3) ? (n0 >> 10) : 0;
  ushort* dst = io.d[sel];
  const float* bias = io.b[sel];
  int ncol = (EPI == 3) ? (n0 & 1023) : n0;

  if (EPI == 3 && sel == 3){
    // ---- V path: bias-add into LDS tile T[l][d] (stride 129), then write
    // Vt[(b*8+hh)*128 + d][l0 + c] = T[sigma(c)][d]  (sigma swaps key bits 2<->3)
    #pragma unroll
    for (int mi = 0; mi < 4; mi++){
      int lr = wm + mi * 16 + quad * 4;
      #pragma unroll
      for (int ni = 0; ni < 4; ni++){
        int d = wn + ni * 16 + l15;
        float bv = bias[ncol + d];
        #pragma unroll
        for (int r = 0; r < 4; r++)
          smem[(lr + r) * 129 + d] = f2bf(acc[mi][ni][r] + bv);
      }
    }
    __syncthreads();
    int b_ = m0 >> 11, l0 = m0 & 2047;
    int hh = ncol >> 7;
    int d = t >> 1, lh = t & 1;
    ushort* vrow = io.d[3] + ((size_t)((b_ * 8 + hh) * 128 + d)) * 2048 + l0 + lh * 64;
    #pragma unroll
    for (int j = 0; j < 64; j += 2){
      int c = lh * 64 + j;
      int x = c & 15;
      int ls = (c & 112) | ((x & 4) << 1) | ((x & 8) >> 1) | (x & 3);
      unsigned int val = (unsigned int)smem[ls * 129 + d] |
                         ((unsigned int)smem[(ls + 1) * 129 + d] << 16);
      *(unsigned int*)(vrow + j) = val;
    }
    return;
  }

  #pragma unroll
  for (int mi = 0; mi < 4; mi++){
    int gm = m0 + wm + mi * 16 + quad * 4;
    #pragma unroll
    for (int ni = 0; ni < 4; ni++){
      int cn = ncol + wn + ni * 16 + l15;
      float bv = bias[cn];
      if (EPI == 3 && sel == 0) bv *= 0.08838834764831845f;  // Wq pre-scaled
      if (EPI == 3 && sel < 2){
        // fused RoPE: pair (even,odd) cols live in lanes lane^1
        int i2 = (cn & 127) >> 1;
        float freq = __builtin_amdgcn_exp2f(-0.20762050f * (float)i2);  // 10000^(-2i/128)
        int odd = cn & 1;
        #pragma unroll
        for (int r = 0; r < 4; r++){
          float val = acc[mi][ni][r] + bv;
          float pv = __shfl_xor(val, 1, 64);
          int pos = (gm + r) & 2047;
          float ang = (float)pos * freq;
          float sv, cv; __sincosf(ang, &sv, &cv);
          float res = odd ? (pv * sv + val * cv) : (val * cv - pv * sv);
          dst[(size_t)(gm + r) * 1024 + cn] = f2bf(res);
        }
      } else {
        #pragma unroll
        for (int r = 0; r < 4; r++){
          float val = acc[mi][ni][r] + bv;
          size_t o = (size_t)(gm + r) * 1024 + cn;
          if (EPI == 1){ outf[o] = resid[o] + val; }
          else if (EPI == 2){
            float sg = __builtin_amdgcn_rcpf(1.f + __expf(-val));
            dst[o] = f2bf(val * val * sg);
          }
          else { dst[o] = f2bf(val); }
        }
      }
    }
  }
}

// ---------------- GEMM 64x128 tile, BK=64, swizzled (512 blocks) ------------
// EPI: 1 = bias + residual -> fp32 ; 2 = bias + p*silu(p) -> bf16
template<int EPI>
__global__ __launch_bounds__(256, 2) void gemm_k2(
    const ushort* __restrict__ A, const ushort* __restrict__ W,
    const float* __restrict__ bias, ushort* __restrict__ dst,
    const float* __restrict__ resid, float* __restrict__ outf){
  __shared__ ushort As[64 * 64];
  __shared__ ushort Bs[128 * 64];
  int m0 = (blockIdx.x >> 3) << 6;
  int n0 = (blockIdx.x & 7) << 7;
  int t = threadIdx.x, lane = t & 63, wv = t >> 6;
  int l15 = lane & 15, quad = lane >> 4;
  int wm = (wv & 1) << 5, wn = (wv >> 1) << 6;
  f32x4 acc[2][4] = {};
  for (int k0 = 0; k0 < 1024; k0 += 64){
    #pragma unroll
    for (int r = 0; r < 6; r++){
      int cb = (r < 2 ? r * 256 : (r - 2) * 256) + wv * 64;
      int c = cb + lane;
      int row = c >> 3, j = c & 7;
      int kk = ((j ^ (row & 7)) << 3);
      if (r < 2){
        __builtin_amdgcn_global_load_lds(
            (const __attribute__((address_space(1))) unsigned int*)(A + (size_t)(m0 + row) * 1024 + k0 + kk),
            (__attribute__((address_space(3))) unsigned int*)&As[cb * 8], 16, 0, 0);
      } else {
        __builtin_amdgcn_global_load_lds(
            (const __attribute__((address_space(1))) unsigned int*)(W + (size_t)(n0 + row) * 1024 + k0 + kk),
            (__attribute__((address_space(3))) unsigned int*)&Bs[cb * 8], 16, 0, 0);
      }
    }
    __syncthreads();
    #pragma unroll
    for (int kd = 0; kd < 2; kd++){
      s16x8 afr[2], bfr[4];
      #pragma unroll
      for (int mi = 0; mi < 2; mi++){
        int R = wm + mi * 16 + l15;
        afr[mi] = *(const s16x8*)&As[R * 64 + (((kd << 2) | quad) ^ (R & 7)) * 8];
      }
      #pragma unroll
      for (int ni = 0; ni < 4; ni++){
        int R = wn + ni * 16 + l15;
        bfr[ni] = *(const s16x8*)&Bs[R * 64 + (((kd << 2) | quad) ^ (R & 7)) * 8];
      }
      #pragma unroll
      for (int mi = 0; mi < 2; mi++)
        #pragma unroll
        for (int ni = 0; ni < 4; ni++)
          acc[mi][ni] = __builtin_amdgcn_mfma_f32_16x16x32_bf16(afr[mi], bfr[ni], acc[mi][ni], 0, 0, 0);
    }
    __syncthreads();
  }
  #pragma unroll
  for (int mi = 0; mi < 2; mi++){
    int gm = m0 + wm + mi * 16 + quad * 4;
    #pragma unroll
    for (int ni = 0; ni < 4; ni++){
      int cn = n0 + wn + ni * 16 + l15;
      float bv = bias[cn];
      #pragma unroll
      for (int r = 0; r < 4; r++){
        float val = acc[mi][ni][r] + bv;
        size_t o = (size_t)(gm + r) * 1024 + cn;
        if (EPI == 1){ outf[o] = resid[o] + val; }
        else {
          float sg = __builtin_amdgcn_rcpf(1.f + __expf(-val));
          dst[o] = f2bf(val * val * sg);
        }
      }
    }
  }
}

// ---------------- causal silu-attention, split-K, 32x32 MFMA ----------------
// 128-q blocks, 64-key tiles, 4 waves x 32 q-rows (proven load-balanced
// 512-block paired grid; blocks i and i+256 sum to 17 iters at 2 blocks/CU).
// Swapped QK^T (mfma(K,Q) -> S^T, col=q=lane&31) keeps P lane-local;
// in-register cvt_pk pack feeds PV directly (sigma absorbed into Vt).
// S pre-scaled via Wq fold. No setprio: intra-block waves are barrier-
// synced every iter, so priority boosts delay staging (R9 lesson).
__global__ __launch_bounds__(256, 2) void attn_kernel(
    const ushort* __restrict__ Q, const ushort* __restrict__ K,
    const ushort* __restrict__ Vt,
    ushort* __restrict__ Po0, ushort* __restrict__ Po1){
  __shared__ ushort Ks[2][64 * 128];
  __shared__ ushort Vs[2][128 * 64];
  int t = threadIdx.x, lane = t & 63, wv = t >> 6;
  int l31 = lane & 31, h = lane >> 5;
  int idx = blockIdx.x;
  int bh = idx & 15;
  int s = idx >> 4;
  int qt = (s < 16) ? (15 - (s >> 1)) : ((s - 16) >> 1);
  int half = s & 1;
  int ntiles = 2 * qt + 2;
  int c0 = qt + 1;
  int klo = half ? c0 : 0;
  int khi = half ? ntiles : c0;
  if (klo >= khi) return;
  int b = bh >> 3, hh = bh & 7;
  int q0 = qt << 7;

  // Q fragments (B-operand): col = q = lane&31, k(hd) = 16*kd + 8*h + j
  s16x8 qf[8];
  const ushort* qbase = Q + (size_t)(b * LQ + q0 + (wv << 5) + l31) * D_ + hh * HD_;
  #pragma unroll
  for (int kd = 0; kd < 8; kd++) qf[kd] = *(const s16x8*)(qbase + kd * 16 + h * 8);

  auto STAGE = [&](int p, int kt){
    int k0 = kt << 6;
    #pragma unroll
    for (int r = 0; r < 4; r++){
      int cb = r * 256 + (wv << 6);    // wave-uniform slot base
      int c = cb + lane;               // 16B slot id 0..1023
      int R = c >> 4, sl = c & 15;
      int gg = sl ^ (R & 7);           // swizzled source granule
      __builtin_amdgcn_global_load_lds(
          (const __attribute__((address_space(1))) unsigned int*)(K + (size_t)(b * LQ + k0 + R) * D_ + hh * HD_ + gg * 8),
          (__attribute__((address_space(3))) unsigned int*)&Ks[p][cb * 8], 16, 0, 0);
    }
    #pragma unroll
    for (int r = 0; r < 4; r++){
      int cb = r * 256 + (wv << 6);
      int c = cb + lane;
      int R = c >> 3, sl = c & 7;
      int gg = sl ^ (R & 7);
      __builtin_amdgcn_global_load_lds(
          (const __attribute__((address_space(1))) unsigned int*)(Vt + (size_t)(bh * HD_ + R) * LQ + k0 + gg * 8),
          (__attribute__((address_space(3))) unsigned int*)&Vs[p][cb * 8], 16, 0, 0);
    }
  };

  f32x16 acc_o[4] = {};
  int qg = q0 + (wv << 5) + l31;

  STAGE(0, klo);
  __syncthreads();
  for (int kt = klo; kt < khi; kt++){
    int p = (kt - klo) & 1;
    if (kt + 1 < khi) STAGE(p ^ 1, kt + 1);
    // swapped QK^T: S^T[key][q], col = q = lane&31
    f32x16 sacc[2] = {};
    #pragma unroll
    for (int kd = 0; kd < 8; kd++){
      #pragma unroll
      for (int kb = 0; kb < 2; kb++){
        int R = (kb << 5) + l31;
        s16x8 af = *(const s16x8*)&Ks[p][(R * 16 + (((kd << 1) | h) ^ (R & 7))) * 8];
        sacc[kb] = __builtin_amdgcn_mfma_f32_32x32x16_bf16(af, qf[kd], sacc[kb], 0, 0, 0);
      }
    }
    // silu + causal mask + in-register pack to PV A-fragments (S pre-scaled)
    int k0 = kt << 6;
    s16x8 pf[4];
    #pragma unroll
    for (int kb = 0; kb < 2; kb++){
      float pvv[16];
      #pragma unroll
      for (int r = 0; r < 16; r++){
        int kg = k0 + (kb << 5) + (r & 3) + ((r >> 2) << 3) + (h << 2);
        float sv = sacc[kb][r];
        float pp = sv * __builtin_amdgcn_rcpf(1.f + __expf(-sv));
        pvv[r] = (kg <= qg) ? pp : 0.f;
      }
      #pragma unroll
      for (int cc = 0; cc < 2; cc++){
        union { u32x4 u; s16x8 v; } w;
        w.u[0] = pkbf(pvv[cc*8+0], pvv[cc*8+1]);
        w.u[1] = pkbf(pvv[cc*8+2], pvv[cc*8+3]);
        w.u[2] = pkbf(pvv[cc*8+4], pvv[cc*8+5]);
        w.u[3] = pkbf(pvv[cc*8+6], pvv[cc*8+7]);
        pf[(kb << 1) | cc] = w.v;
      }
    }
    // PV: O[q][d] += P * V  (V columns sigma-permuted to match pf key order)
    #pragma unroll
    for (int kv = 0; kv < 4; kv++){
      #pragma unroll
      for (int nt = 0; nt < 4; nt++){
        int R = (nt << 5) + l31;
        s16x8 vf = *(const s16x8*)&Vs[p][(R * 8 + (((kv << 1) | h) ^ (R & 7))) * 8];
        acc_o[nt] = __builtin_amdgcn_mfma_f32_32x32x16_bf16(pf[kv], vf, acc_o[nt], 0, 0, 0);
      }
    }
    __syncthreads();
  }
  ushort* Po = half ? Po1 : Po0;
  #pragma unroll
  for (int nt = 0; nt < 4; nt++){
    #pragma unroll
    for (int r = 0; r < 16; r++){
      int qq = q0 + (wv << 5) + (r & 3) + ((r >> 2) << 3) + (h << 2);
      int dd = (nt << 5) + l31;
      Po[(size_t)(b * LQ + qq) * D_ + hh * HD_ + dd] = f2bf(acc_o[nt][r]);
    }
  }
}

// ---------------- attn partial reduce: (P0 + P1) * U -> bf16 ----------------
__global__ __launch_bounds__(256) void attn_reduce(
    const ushort* __restrict__ Po0, const ushort* __restrict__ Po1,
    const ushort* __restrict__ U, ushort* __restrict__ Aout){
  int i = (blockIdx.x * 256 + threadIdx.x) * 4;   // 4M elems total
  ushort4 p0 = *(const ushort4*)(Po0 + i);
  ushort4 p1 = *(const ushort4*)(Po1 + i);
  float v0 = bf2f(p0.x) + bf2f(p1.x);
  float v1 = bf2f(p0.y) + bf2f(p1.y);
  float v2 = bf2f(p0.z) + bf2f(p1.z);
  float v3 = bf2f(p0.w) + bf2f(p1.w);
  ushort4 u = *(const ushort4*)(U + i);
  ushort4 o;
  o.x = f2bf(v0 * bf2f(u.x)); o.y = f2bf(v1 * bf2f(u.y));
  o.z = f2bf(v2 * bf2f(u.z)); o.w = f2bf(v3 * bf2f(u.w));
  *(ushort4*)(Aout + i) = o;
}

// ---------------- launcher --------------------------------------------------
extern "C" void kernel_launch(void* const* d_in, const int* in_sizes, int n_in,
                              void* d_out, int out_size, void* d_ws, size_t ws_size,
                              hipStream_t stream){
  const float* seqs = (const float*)d_in[0];
  const float* bq = (const float*)d_in[3];
  const float* bk = (const float*)d_in[5];
  const float* bu = (const float*)d_in[7];
  const float* bv = (const float*)d_in[9];
  const float* bo = (const float*)d_in[11];
  const float* b1 = (const float*)d_in[13];
  const float* b2 = (const float*)d_in[15];
  const float* ln1g = (const float*)d_in[16];
  const float* ln1b = (const float*)d_in[17];
  const float* ln2g = (const float*)d_in[18];
  const float* ln2b = (const float*)d_in[19];
  const float* lnfg = (const float*)d_in[20];
  const float* lnfb = (const float*)d_in[21];

  char* base = (char*)d_ws;
  const size_t MB = 1u << 20;
  if (ws_size < 78 * MB) return;  // defensive
  ushort* wbf = (ushort*)base;                   // 14 MB
  ushort* h   = (ushort*)(base + 14 * MB);       // 8 MB (ln out; attn Po0; attn out)
  ushort* Qb  = (ushort*)(base + 22 * MB);       // 8 MB (also MLP hidden)
  ushort* Kb  = (ushort*)(base + 30 * MB);       // 8 MB
  ushort* Ub  = (ushort*)(base + 38 * MB);       // 8 MB
  ushort* Vb  = (ushort*)(base + 46 * MB);       // 8 MB (attn Po1)
  ushort* Vt  = (ushort*)(base + 54 * MB);       // 8 MB (written by gemm_k sel==3)
  float*  xb  = (float*)(base + 62 * MB);        // 16 MB
  ushort* ab  = h;

  const size_t DD = 1048576;
  for (int i = 0; i < 2; i++){
    WP wp;
    for (int j = 0; j < 7; j++)
      wp.s[j] = (const float*)d_in[2 + 2 * j] + (size_t)i * DD;
    convert_weights<<<7 * 128, 256, 0, stream>>>(wp, wbf);
    const ushort* Wl = wbf;
    const float* xin = (i == 0) ? seqs : xb;
    ln_kernel<0><<<4096, 256, 0, stream>>>(xin, ln1g + i * D_, ln1b + i * D_, nullptr, h);
    // fused QKUV projection (N=4096): RoPE on Q,K; V written transposed to Vt
    P4 io_qkuv = {{Qb, Kb, Ub, Vt}, {bq + i * D_, bk + i * D_, bu + i * D_, bv + i * D_}};
    gemm_k<3, 32><<<1024, 256, 0, stream>>>(h, Wl, io_qkuv, nullptr, nullptr);
    attn_kernel<<<512, 256, 0, stream>>>(Qb, Kb, Vt, ab, Vb);
    attn_reduce<<<4096, 256, 0, stream>>>(ab, Vb, Ub, ab);
    gemm_k2<1><<<512, 256, 0, stream>>>(ab, Wl + 4 * DD, bo + i * D_, nullptr, xin, xb);
    ln_kernel<0><<<4096, 256, 0, stream>>>(xb, ln2g + i * D_, ln2b + i * D_, nullptr, h);
    gemm_k2<2><<<512, 256, 0, stream>>>(h, Wl + 5 * DD, b1 + i * D_, Qb, nullptr, nullptr);
    gemm_k2<1><<<512, 256, 0, stream>>>(Qb, Wl + 6 * DD, b2 + i * D_, nullptr, xb, xb);
  }
  ln_kernel<1><<<4096, 256, 0, stream>>>(xb, lnfg, lnfb, (float*)d_out, nullptr);
}